// Round 10
// baseline (201.671 us; speedup 1.0000x reference)
//
#include <hip/hip_runtime.h>
#include <hip/hip_bf16.h>
#include <stdint.h>

// DenseGraphAttentionHead N=8192, IN=512, OUT=256, ~50% dense int32 mask.
//
// Pipeline (k_mask DELETED — raw mask streamed inside k_attn):
//   k_convert_w : W f32 -> bf16 chunked (16B chunk (kb,row) at kb*2048+row*8).
//   k_wh        : Wh = nodes@W^T + b (mfma) -> WhL chunked bf16 + s1/s2 f32.
//   k_prep      : exp-factorization tables (lrelu lets exp factor):
//                 P = mask * (s1+s2>0 ? e^{s1}e^{s2} : e^{.2s1}e^{.2s2}).
//   k_attn      : masked-softmax @ Wh. Grid 128rt x 8jc = 1024 blocks = 4/CU;
//                 block 256 thr = 4 waves = 2 rowgroups(32) x 2 colhalves
//                 (128); acc 64 AGPR. WhL j-slice dbl-buffered via
//                 global_load_lds; PK in LDS; mask int32 read DIRECTLY from
//                 global per lane (4x dwordx4/step, nontemporal, 1-step reg
//                 prefetch). Per row+step the wave touches one contiguous
//                 128B window = one L2 line -> HBM mask traffic = 268MB once;
//                 ns-pair re-read hits L2. The mask stream fills k_attn's
//                 idle VMEM pipe (it was latency-bound with ~2% HBM).
//   k_comb      : out = sum_jc(pnum) / sum_jc(pden), 8 partials.
//
// MFMA conventions (verified R1-R9 on this problem):
//   A frag: lane&15 = m, k = (lane>>4)*8 + i ; B same per-lane k order
//   D: col = lane&15, row = (lane>>4)*4 + reg

#define NN 8192
#define IND 512
#define OUTD 256

typedef __attribute__((ext_vector_type(8))) short short8;
typedef __attribute__((ext_vector_type(4))) short short4v;
typedef __attribute__((ext_vector_type(4))) float f32x4;
typedef __attribute__((ext_vector_type(4))) int i32x4;
typedef __attribute__((ext_vector_type(4))) unsigned int u32x4;

#define AS_GLOBAL __attribute__((address_space(1)))
#define AS_LDS __attribute__((address_space(3)))

static __device__ __forceinline__ short f2bf(float f) {
  return __builtin_bit_cast(short, __float2bfloat16(f));
}

extern "C" __global__ __launch_bounds__(256) void k_convert_w(
    const float* __restrict__ W, short* __restrict__ W2) {
  const int t = blockIdx.x * 256 + threadIdx.x;  // 16384 threads
  const int row = t >> 6, kb = t & 63;
  const float* src = W + row * IND + kb * 8;
  f32x4 x0 = *(const f32x4*)src;
  f32x4 x1 = *(const f32x4*)(src + 4);
  short8 o;
  o[0] = f2bf(x0[0]); o[1] = f2bf(x0[1]); o[2] = f2bf(x0[2]); o[3] = f2bf(x0[3]);
  o[4] = f2bf(x1[0]); o[5] = f2bf(x1[1]); o[6] = f2bf(x1[2]); o[7] = f2bf(x1[3]);
  *(short8*)(W2 + (size_t)kb * 2048 + row * 8) = o;
}

extern "C" __global__ __launch_bounds__(128) void k_wh(
    const float* __restrict__ nodes, const short* __restrict__ W2,
    const float* __restrict__ Wb, const float* __restrict__ a1w,
    const float* __restrict__ a1b, const float* __restrict__ a2w,
    const float* __restrict__ a2b, short* __restrict__ WhL,
    float* __restrict__ s1, float* __restrict__ s2) {
  const int tid = threadIdx.x;
  const int wv = tid >> 6, lane = tid & 63, g = lane >> 4, m = lane & 15;
  const int rowbase = blockIdx.x * 32 + wv * 16;

  f32x4 acc[16];
#pragma unroll
  for (int nf = 0; nf < 16; ++nf) acc[nf] = (f32x4){0.f, 0.f, 0.f, 0.f};

  const float* arow = nodes + (size_t)(rowbase + m) * IND;
  const short* bb = W2 + (size_t)g * 2048 + m * 8;
#pragma unroll 4
  for (int k0 = 0; k0 < IND; k0 += 32) {
    const float* ap = arow + k0 + g * 8;
    f32x4 x0 = *(const f32x4*)ap;
    f32x4 x1 = *(const f32x4*)(ap + 4);
    short8 af;
    af[0] = f2bf(x0[0]); af[1] = f2bf(x0[1]); af[2] = f2bf(x0[2]); af[3] = f2bf(x0[3]);
    af[4] = f2bf(x1[0]); af[5] = f2bf(x1[1]); af[6] = f2bf(x1[2]); af[7] = f2bf(x1[3]);
    const short* bk = bb + (size_t)(k0 >> 3) * 2048;
#pragma unroll
    for (int nf = 0; nf < 16; ++nf) {
      short8 bf = *(const short8*)(bk + nf * 128);
      acc[nf] = __builtin_amdgcn_mfma_f32_16x16x32_bf16(af, bf, acc[nf], 0, 0, 0);
    }
  }

  float p1[4] = {0.f, 0.f, 0.f, 0.f}, p2[4] = {0.f, 0.f, 0.f, 0.f};
#pragma unroll
  for (int nf = 0; nf < 16; ++nf) {
    const int n = nf * 16 + m;
    const float b = Wb[n], c1 = a1w[n], c2 = a2w[n];
#pragma unroll
    for (int r = 0; r < 4; ++r) {
      float v = acc[nf][r] + b;
      acc[nf][r] = v;
      p1[r] += c1 * v;
      p2[r] += c2 * v;
    }
  }
#pragma unroll
  for (int off = 1; off < 16; off <<= 1) {
#pragma unroll
    for (int r = 0; r < 4; ++r) {
      p1[r] += __shfl_xor(p1[r], off);
      p2[r] += __shfl_xor(p2[r], off);
    }
  }
  if (m == 0) {
    const float b1 = a1b[0], b2 = a2b[0];
#pragma unroll
    for (int r = 0; r < 4; ++r) {
      const int row = rowbase + g * 4 + r;
      s1[row] = p1[r] + b1;
      s2[row] = p2[r] + b2;
    }
  }

  const size_t cbase = ((size_t)(rowbase >> 3) + (g >> 1)) * 2048 + (g & 1) * 4;
#pragma unroll
  for (int nf = 0; nf < 16; ++nf) {
    short4v o;
#pragma unroll
    for (int r = 0; r < 4; ++r) o[r] = f2bf(acc[nf][r]);
    *(short4v*)(WhL + cbase + (size_t)(nf * 16 + m) * 8) = o;
  }
}

// exp-factorization tables
extern "C" __global__ __launch_bounds__(256) void k_prep(
    const float* __restrict__ s1, const float* __restrict__ s2,
    float* __restrict__ sAC, uint32_t* __restrict__ sPK) {
  const int i = blockIdx.x * 256 + threadIdx.x;  // 8192 threads
  const float v1 = s1[i], v2 = s2[i];
  sAC[i] = __expf(v1);
  sAC[NN + i] = __expf(0.2f * v1);
  const float B = __expf(v2), D = __expf(0.2f * v2);
  sPK[2 * i] = __builtin_bit_cast(uint32_t, B);
  sPK[2 * i + 1] =
      ((uint32_t)(uint16_t)f2bf(D) << 16) | (uint16_t)(uint16_t)f2bf(v2);
}

extern "C" __global__ __launch_bounds__(256, 4) void k_attn(
    const int* __restrict__ mask, const short* __restrict__ WhL,
    const float* __restrict__ s1, const float* __restrict__ sAC,
    const uint32_t* __restrict__ sPK,
    float* __restrict__ pnum, float* __restrict__ pden) {
  __shared__ short Bs[2][8192];     // 32 KiB dbl-buffered WhL j-slice
  __shared__ uint32_t PKs[2048];    // 8 KiB: {f32 B, u32 D16|s2bf} x 1024 j

  const int tid = threadIdx.x;
  const int w = tid >> 6, lane = tid & 63, g = lane >> 4, m = lane & 15;
  const int rt = blockIdx.x >> 3, jc = blockIdx.x & 7;
  const int rg = w & 1, ns = w >> 1;
  const int rb = rt * 64 + rg * 32;

  // per-lane row constants (rows rb+m and rb+16+m)
  const float T0 = -s1[rb + m],        T1 = -s1[rb + 16 + m];
  const float A0 = sAC[rb + m],        A1 = sAC[rb + 16 + m];
  const float C0 = sAC[NN + rb + m],   C1 = sAC[NN + rb + 16 + m];

  f32x4 acc0[8], acc1[8];
#pragma unroll
  for (int nf = 0; nf < 8; ++nf) {
    acc0[nf] = (f32x4){0.f, 0.f, 0.f, 0.f};
    acc1[nf] = (f32x4){0.f, 0.f, 0.f, 0.f};
  }
  float den0 = 0.f, den1 = 0.f;

  // mask row pointers: lane (g,m) covers ints [g*8, g*8+8) of its rows'
  // current 32-wide window. Per row+step the 4 g-groups' 4 loads cover one
  // contiguous 128B window = one L2 line.
  const int* mr0 = mask + (size_t)(rb + m) * NN + jc * 1024 + g * 8;
  const int* mr1 = mr0 + (size_t)16 * NN;
  const short* gWu = WhL + (size_t)jc * 262144 + w * 2048 + lane * 8;

  // prologue: stage PK slice (8 KB) + WhL slice 0 (16 KB), prefetch mask u=0
#pragma unroll
  for (int c = 0; c < 2; ++c) {
    __builtin_amdgcn_global_load_lds(
        (const AS_GLOBAL void*)((const char*)sPK + (size_t)jc * 8192 +
                                w * 2048 + c * 1024 + lane * 16),
        (AS_LDS void*)((char*)PKs + w * 2048 + c * 1024), 16, 0, 0);
  }
#pragma unroll
  for (int c = 0; c < 4; ++c) {
    __builtin_amdgcn_global_load_lds(
        (const AS_GLOBAL void*)(gWu + c * 512),
        (AS_LDS void*)(&Bs[0][w * 2048 + c * 512]), 16, 0, 0);
  }
  i32x4 cm0a = __builtin_nontemporal_load((const i32x4*)mr0);
  i32x4 cm0b = __builtin_nontemporal_load((const i32x4*)(mr0 + 4));
  i32x4 cm1a = __builtin_nontemporal_load((const i32x4*)mr1);
  i32x4 cm1b = __builtin_nontemporal_load((const i32x4*)(mr1 + 4));
  __syncthreads();

  auto build = [&](float T, float A, float C, const i32x4& lo, const i32x4& hi,
                   const u32x4& q0, const u32x4& q1,
                   const u32x4& q2, const u32x4& q3, float& den) -> short8 {
    const uint32_t Bv[8] = {q0[0], q0[2], q1[0], q1[2],
                            q2[0], q2[2], q3[0], q3[2]};
    const uint32_t Dv[8] = {q0[1], q0[3], q1[1], q1[3],
                            q2[1], q2[3], q3[1], q3[3]};
    short8 af;
#pragma unroll
    for (int i = 0; i < 8; ++i) {
      const float s2v = __builtin_bit_cast(float, Dv[i] << 16);
      const bool pos = s2v > T;
      const float wv = __builtin_bit_cast(float, pos ? Bv[i] : (Dv[i] & 0xFFFF0000u));
      const float a = pos ? A : C;
      const float val = wv * a;
      const int mv = (i < 4) ? lo[i] : hi[i - 4];
      const float pv = (mv != 0) ? val : 0.f;
      den += pv;
      af[i] = f2bf(pv);
    }
    return af;
  };

  for (int u = 0; u < 32; ++u) {
    // 1. async-stage WhL slice u+1 into the other buffer
    if (u < 31) {
      const short* gn = gWu + (size_t)(u + 1) * 8192;
      short* ld = &Bs[(u + 1) & 1][w * 2048];
#pragma unroll
      for (int c = 0; c < 4; ++c) {
        __builtin_amdgcn_global_load_lds(
            (const AS_GLOBAL void*)(gn + c * 512),
            (AS_LDS void*)(ld + c * 512), 16, 0, 0);
      }
    }
    // 2. prefetch next step's mask ints (1-deep, nontemporal)
    const int un = (u < 31) ? u + 1 : 31;
    i32x4 nm0a = __builtin_nontemporal_load((const i32x4*)(mr0 + un * 32));
    i32x4 nm0b = __builtin_nontemporal_load((const i32x4*)(mr0 + un * 32 + 4));
    i32x4 nm1a = __builtin_nontemporal_load((const i32x4*)(mr1 + un * 32));
    i32x4 nm1b = __builtin_nontemporal_load((const i32x4*)(mr1 + un * 32 + 4));

    // 3. compute step u: PK from LDS (broadcast), exp-free P build, 16 MFMA
    const uint32_t* pk = &PKs[(u * 32 + g * 8) * 2];
    const u32x4 q0 = *(const u32x4*)(pk + 0);
    const u32x4 q1 = *(const u32x4*)(pk + 4);
    const u32x4 q2 = *(const u32x4*)(pk + 8);
    const u32x4 q3 = *(const u32x4*)(pk + 12);
    short8 af0 = build(T0, A0, C0, cm0a, cm0b, q0, q1, q2, q3, den0);
    short8 af1 = build(T1, A1, C1, cm1a, cm1b, q0, q1, q2, q3, den1);
    const short* bl = &Bs[u & 1][g * 2048 + (ns * 128 + m) * 8];
#pragma unroll
    for (int nf = 0; nf < 8; ++nf) {
      short8 bf = *(const short8*)(bl + nf * 128);
      acc0[nf] = __builtin_amdgcn_mfma_f32_16x16x32_bf16(af0, bf, acc0[nf], 0, 0, 0);
      acc1[nf] = __builtin_amdgcn_mfma_f32_16x16x32_bf16(af1, bf, acc1[nf], 0, 0, 0);
    }
    cm0a = nm0a; cm0b = nm0b; cm1a = nm1a; cm1b = nm1b;
    // 4. single barrier per step
    __syncthreads();
  }

  den0 += __shfl_xor(den0, 16); den0 += __shfl_xor(den0, 32);
  den1 += __shfl_xor(den1, 16); den1 += __shfl_xor(den1, 32);
  if (ns == 0 && lane < 16) {
    pden[jc * NN + rb + m] = den0;
    pden[jc * NN + rb + 16 + m] = den1;
  }

  float* pn = pnum + (size_t)jc * NN * OUTD + (size_t)rb * OUTD + ns * 128;
#pragma unroll
  for (int r = 0; r < 4; ++r) {
    const int q = g * 4 + r;
#pragma unroll
    for (int nf = 0; nf < 8; ++nf) {
      pn[(size_t)q * OUTD + nf * 16 + m] = acc0[nf][r];
      pn[(size_t)(16 + q) * OUTD + nf * 16 + m] = acc1[nf][r];
    }
  }
}

extern "C" __global__ __launch_bounds__(256) void k_comb(
    const float* __restrict__ pnum, const float* __restrict__ pden,
    float* __restrict__ out) {
  const int idx = blockIdx.x * 256 + threadIdx.x;  // 524288 threads
  const int row = idx >> 6, c4 = (idx & 63) * 4;
  f32x4 s = (f32x4){0.f, 0.f, 0.f, 0.f};
  float d = 0.f;
#pragma unroll
  for (int jc = 0; jc < 8; ++jc) {
    f32x4 v = *(const f32x4*)(pnum + ((size_t)jc * NN + row) * OUTD + c4);
    s += v;
    d += pden[jc * NN + row];
  }
  const float inv = 1.f / d;
  *(f32x4*)(out + (size_t)row * OUTD + c4) = s * inv;
}

extern "C" void kernel_launch(void* const* d_in, const int* in_sizes, int n_in,
                              void* d_out, int out_size, void* d_ws, size_t ws_size,
                              hipStream_t stream) {
  const float* nodes = (const float*)d_in[0];
  const int*   mask  = (const int*)d_in[1];
  const float* W_w   = (const float*)d_in[2];
  const float* W_b   = (const float*)d_in[3];
  const float* a1w   = (const float*)d_in[4];
  const float* a1b   = (const float*)d_in[5];
  const float* a2w   = (const float*)d_in[6];
  const float* a2b   = (const float*)d_in[7];
  float* out = (float*)d_out;

  char* ws = (char*)d_ws;
  short*    WhL  = (short*)(ws);                                  // 4 MiB
  float*    s1   = (float*)(ws + (size_t)4  * 1024 * 1024);       // 32 KiB
  float*    s2   = (float*)(ws + (size_t)4  * 1024 * 1024 + 32768);
  short*    W2   = (short*)(ws + (size_t)4  * 1024 * 1024 + 65536); // 256 KiB
  float*    sAC  = (float*)(ws + (size_t)13 * 1024 * 1024);       // 64 KiB
  uint32_t* sPK  = (uint32_t*)(ws + (size_t)14 * 1024 * 1024);    // 64 KiB
  float*    pnum = (float*)(ws + (size_t)16 * 1024 * 1024);       // 64 MiB
  float*    pden = (float*)(ws + (size_t)96 * 1024 * 1024);       // 256 KiB

  hipLaunchKernelGGL(k_convert_w, dim3(64), dim3(256), 0, stream, W_w, W2);
  hipLaunchKernelGGL(k_wh, dim3(256), dim3(128), 0, stream,
                     nodes, W2, W_b, a1w, a1b, a2w, a2b, WhL, s1, s2);
  hipLaunchKernelGGL(k_prep, dim3(32), dim3(256), 0, stream, s1, s2, sAC, sPK);
  hipLaunchKernelGGL(k_attn, dim3(1024), dim3(256), 0, stream,
                     mask, WhL, s1, sAC, sPK, pnum, pden);
  hipLaunchKernelGGL(k_comb, dim3(2048), dim3(256), 0, stream,
                     pnum, pden, out);
}